// Round 6
// baseline (522.445 us; speedup 1.0000x reference)
//
#include <hip/hip_runtime.h>
#include <math.h>

// ---------------------------------------------------------------------------
// SLAY sampled-softmax loss on MI355X.
// H=4 heads, D=128, P=16 anchors, M=32 features, R=2 quad nodes, E=512.
// B=512, S=64, K=5, L=32768 labels, VOCAB=100000.
//
// Decomposition (never materialize phi matrices):
//   phi[n,(r,h,p,m)] = poly[n,h,p] * prf[r,n,h,m]
//   Z[r,h,p,m]  = sum_l poly_W[l,h,p]*prf_W[r,l,h,m]
//   denom[b]    = sum_f phi_q[b,f]*Z[f]
//   nums[b,k]   = sum_h (poly_W.poly_q)[h] * sum_r (prf_W.prf_q)[r,h]
//
// R5: k_labels LDS halved (two 64-d staging passes; ex[64][85] is the whole
// 21.8 KB footprint -> 6-7 blocks/CU vs 4), coefficients packed [h][w][d][24]
// (16B-aligned, zero-padded per-wave rows -> clean s_load_dwordx8 stream),
// Z-partial uses all 256 threads, feat store is ballot-driven.
// ---------------------------------------------------------------------------

namespace {
constexpr double Cq  = 2.0 + 1e-6;
constexpr double QN0 = 0.5857864376269049  / Cq;   // laggauss(2) nodes / C
constexpr double QN1 = 3.414213562373095   / Cq;
constexpr double QW0 = 0.8535533905932738  / Cq;   // laggauss(2) weights / C
constexpr double QW1 = 0.14644660940672624 / Cq;

// workspace float offsets
constexpr size_t OFF_POLYQ = 0;                    // 512*4*16   [b][h][p]
constexpr size_t OFF_PRFQ  = 32768;                // 512*2*4*32 [b][r][h][m]
constexpr size_t OFF_Z     = OFF_PRFQ + 131072;    // 4096       [r][h][p][m]
constexpr size_t OFF_ANCT  = OFF_Z + 4096;         // 128*16 anchors^T [d][p]
constexpr size_t OFF_SLOT  = OFF_ANCT + 2048;      // 32768 ints: label->slot|-1
constexpr size_t OFF_FEAT  = OFF_SLOT + 32768;     // 2560*4*80 [slot][h][poly|prf]
constexpr size_t OFF_WPACK = OFF_FEAT + 819200;    // 4*4*128*24 [h][w][d][24]
constexpr size_t OFF_ZPART = OFF_WPACK + 49152;    // 2048*1024 per-block Z partials
}

// grid-parallel init: slot=-1, Z=0, out=0, anchors^T, Wpack[h][w][d][24]
// (wave w's outputs o = w*21 + c, c<21, o<80; rest zero-padded, 16B-aligned)
__global__ void k_setup_a(const float* __restrict__ anchors,
                          const float* __restrict__ omega,
                          int* __restrict__ slot, float* __restrict__ Z,
                          float* __restrict__ out, float* __restrict__ anct,
                          float* __restrict__ Wpack)
{
    int t = blockIdx.x * 256 + threadIdx.x;           // 64*256 = 16384 threads
    for (int i = t; i < 32768; i += 16384) slot[i] = -1;
    if (t < 4096) Z[t] = 0.f;
    if (t == 0) out[0] = 0.f;
    if (t < 2048) {                                   // anct[d][p]
        int p = t & 15, d = t >> 4;
        anct[t] = anchors[p * 128 + d];
    }
    for (int i = t; i < 4 * 4 * 128 * 24; i += 16384) {
        int c = i % 24, d = (i / 24) & 127, w = (i / (24 * 128)) & 3, h = i / (24 * 128 * 4);
        int o = w * 21 + c;
        float v = 0.f;
        if (c < 21 && o < 80) {
            if (o < 16) v = anchors[o * 128 + d];
            else {
                int r = (o - 16) >> 5, m = (o - 16) & 31;
                v = omega[(((r * 4 + h) * 128) + d) * 32 + m];
            }
        }
        Wpack[i] = v;
    }
}

// slot scatter (must run after slot init -> separate dispatch)
__global__ void k_setup_b(const int* __restrict__ labels, int* __restrict__ slot)
{
    int i = blockIdx.x * 256 + threadIdx.x;
    if (i < 2560) slot[max(labels[i], 0)] = i;
}

// fused: masked mean embedding -> LDS, then query features. One block per b.
__global__ void __launch_bounds__(256) k_embed_feat(const int* __restrict__ idx,
        const float* __restrict__ mask, const float* __restrict__ emb,
        const float* __restrict__ anct, const float* __restrict__ omega,
        float* __restrict__ polyq, float* __restrict__ prfq)
{
    __shared__ float xs[512];
    __shared__ float rnS[4];
    int b = blockIdx.x, t = threadIdx.x;

    float2 acc = make_float2(0.f, 0.f);
    float msum = 0.f;
#pragma unroll 8
    for (int s = 0; s < 64; ++s) {
        float mv = mask[b * 64 + s];
        const float2* row = (const float2*)(emb + (size_t)idx[b * 64 + s] * 512);
        float2 v = row[t];
        acc.x = fmaf(mv, v.x, acc.x);
        acc.y = fmaf(mv, v.y, acc.y);
        msum += mv;
    }
    float inv = 1.0f / fmaxf(msum, 1e-9f);
    xs[2 * t]     = acc.x * inv;
    xs[2 * t + 1] = acc.y * inv;
    __syncthreads();

    int w = t >> 6, lane = t & 63;
    {
        float v0 = xs[w * 128 + lane], v1 = xs[w * 128 + 64 + lane];
        float ss = fmaf(v0, v0, v1 * v1);
#pragma unroll
        for (int o = 1; o < 64; o <<= 1) ss += __shfl_xor(ss, o, 64);
        if (lane == 0) rnS[w] = 1.0f / fmaxf(sqrtf(ss), 1e-6f);
    }
    __syncthreads();

    const float s_[2] = {(float)QN0, (float)QN1};
    const float g_[2] = {sqrtf(2.0f * (float)QN0), sqrtf(2.0f * (float)QN1)};
    const float c_[2] = {sqrtf((float)QW0) * 0.17677669529663687f,
                         sqrtf((float)QW1) * 0.17677669529663687f};

    for (int tau = t; tau < 320; tau += 256) {
        int h = tau / 80, j = tau - h * 80;
        const float* xh = xs + h * 128;
        float a = 0.f;
        if (j < 16) {
            for (int d = 0; d < 128; ++d) a = fmaf(xh[d], anct[d * 16 + j], a);
            float v = a * rnS[h];
            polyq[(b * 4 + h) * 16 + j] = v * v * 0.25f;
        } else {
            int rj = j - 16, r = rj >> 5, m = rj & 31;
            const float* om = omega + ((size_t)(r * 4 + h) * 128) * 32 + m;
            for (int d = 0; d < 128; ++d) a = fmaf(xh[d], om[d * 32], a);
            float z = a * rnS[h] * g_[r] - s_[r];
            z = fminf(fmaxf(z, -10.f), 10.f);
            prfq[((b * 2 + r) * 4 + h) * 32 + m] = expf(z) * c_[r];
        }
    }
}

// dominant kernel. Block = 64 labels x 1 head, 256 threads (4 waves).
// d processed in two 64-deep halves; x tile staged per half (16 KB, coalesced).
// Wave w accumulates its 21 outputs from Wpack[h][w][d][24] (wave-uniform
// 16B-aligned scalar loads). Total LDS = ex[64*85] = 21.8 KB.
__global__ void __launch_bounds__(256, 6) k_labels(const float* __restrict__ ck,
                                                   const float* __restrict__ Wpack,
                                                   const int* __restrict__ slot,
                                                   float* __restrict__ feat,
                                                   float* __restrict__ Zpart)
{
    __shared__ float ex[5440];        // xs[64][64] during accum; ex[64][85] after
    __shared__ int slS[64];
    __shared__ unsigned long long hitmaskS;

    int t = threadIdx.x, w = t >> 6, lane = t & 63;
    int bid = blockIdx.x, g = bid >> 2, h = bid & 3;
    int l0 = g * 64;

    int sl = -1;
    if (t < 64) { sl = slot[l0 + t]; slS[t] = sl; }
    if (w == 0) {
        unsigned long long m = __ballot(sl >= 0);
        if (lane == 0) hitmaskS = m;
    }

    const float* src = ck + (size_t)h * 128 * 32768 + l0;
    const float* wrow = Wpack + ((size_t)h * 4 + w) * 128 * 24;

    float acc[21] = {};
    float sumsq = 0.f;
#pragma unroll
    for (int half = 0; half < 2; ++half) {
        __syncthreads();
        const float* s0 = src + (size_t)(half * 64) * 32768;
#pragma unroll
        for (int k = 0; k < 16; ++k) {
            int idx = k * 256 + t;                 // d = idx>>6, lab = idx&63
            ex[idx] = s0[(size_t)(idx >> 6) * 32768 + (idx & 63)];
        }
        __syncthreads();
        const float* crow = wrow + half * 64 * 24;
        for (int d = 0; d < 64; ++d) {
            float xv = ex[d * 64 + lane];
            sumsq = fmaf(xv, xv, sumsq);
            const float* c = crow + d * 24;
#pragma unroll
            for (int i = 0; i < 21; ++i) acc[i] = fmaf(xv, c[i], acc[i]);
        }
    }
    __syncthreads();                  // all waves done reading xs

    // exchange into ex[label][85]
#pragma unroll
    for (int i = 0; i < 21; ++i) {
        int o = w * 21 + i;
        if (o < 80) ex[lane * 85 + o] = acc[i];
    }
    if (w == 3) ex[lane * 85 + 80] = sumsq;
    __syncthreads();

    // finalize in place: thread (l = t&63, part = t>>6) handles 20 outputs
    {
        int l = t & 63, part = t >> 6, o0 = part * 20;
        float rn = 1.0f / fmaxf(sqrtf(ex[l * 85 + 80]), 1e-6f);
        const float s_[2] = {(float)QN0, (float)QN1};
        const float g_[2] = {sqrtf(2.0f * (float)QN0), sqrtf(2.0f * (float)QN1)};
        const float c_[2] = {sqrtf((float)QW0) * 0.17677669529663687f,
                             sqrtf((float)QW1) * 0.17677669529663687f};
#pragma unroll
        for (int i = 0; i < 20; ++i) {
            int o = o0 + i;
            float v = ex[l * 85 + o];
            if (o < 16) {
                v = v * rn;
                v = v * v * 0.25f;
            } else {
                int r = (o - 16) >> 5;
                float z = v * rn * g_[r] - s_[r];
                z = fminf(fmaxf(z, -10.f), 10.f);
                v = expf(z) * c_[r];
            }
            ex[l * 85 + o] = v;
        }
    }
    __syncthreads();

    // selective compact feature store (ballot-driven: ~5 hits per block avg)
    unsigned long long hits = hitmaskS;
    while (hits) {
        int j = __builtin_ctzll(hits);
        hits &= hits - 1;
        int s = slS[j];
        if (t < 80) feat[((size_t)s * 4 + h) * 80 + t] = ex[j * 85 + t];
    }

    // Z partial: thread owns (r = t>>7, p = (t>>3)&15, m4 = t&7) -> 4 m's
    {
        int r = t >> 7, p = (t >> 3) & 15, m4 = t & 7;
        float z0 = 0.f, z1 = 0.f, z2 = 0.f, z3 = 0.f;
        for (int j = 0; j < 64; ++j) {
            const float* row = ex + j * 85;
            float pv = row[p];
            const float* pf = row + 16 + r * 32 + m4 * 4;
            z0 = fmaf(pv, pf[0], z0);
            z1 = fmaf(pv, pf[1], z1);
            z2 = fmaf(pv, pf[2], z2);
            z3 = fmaf(pv, pf[3], z3);
        }
        float* zp = Zpart + (size_t)bid * 1024 + (r * 16 + p) * 32 + m4 * 4;
        *(float4*)zp = make_float4(z0, z1, z2, z3);
    }
}

// sum the 2048 per-block Z partials into Z[r][h][p][m] (Z zeroed in setup_a)
__global__ void k_zreduce(const float* __restrict__ Zpart, float* __restrict__ Z)
{
    int tid = blockIdx.x * 256 + threadIdx.x;   // 128*256 = 32768
    int e = tid & 1023, h = (tid >> 10) & 3, chunk = tid >> 12;   // 8 chunks of 64 groups
    float sum = 0.f;
    int g0 = chunk * 64;
#pragma unroll 4
    for (int g = g0; g < g0 + 64; ++g)
        sum += Zpart[(size_t)((g << 2) | h) * 1024 + e];
    atomicAdd(&Z[(e >> 9) * 2048 + h * 512 + (e & 511)], sum);
}

// fused denom + loss: one wave per batch row b
__global__ void k_final(const float* __restrict__ polyq, const float* __restrict__ prfq,
                        const float* __restrict__ Z, const int* __restrict__ labels,
                        const float* __restrict__ lmask, const int* __restrict__ slot,
                        const float* __restrict__ feat, float* __restrict__ out)
{
    int t = threadIdx.x, lane = t & 63;
    int b = blockIdx.x * 4 + (t >> 6);

    float acc = 0.f;
    for (int i = 0; i < 64; ++i) {
        int f = i * 64 + lane;                         // coalesced Z reads
        int m = f & 31, p = (f >> 5) & 15, hh = (f >> 9) & 3, r = f >> 11;
        float phi = polyq[(b * 4 + hh) * 16 + p] * prfq[((b * 2 + r) * 4 + hh) * 32 + m];
        acc = fmaf(phi, Z[f], acc);
    }
#pragma unroll
    for (int o = 1; o < 64; o <<= 1) acc += __shfl_xor(acc, o, 64);
    float logZb = logf(acc + 1e-6f);                   // all lanes hold the sum

    if (lane < 20) {                                   // lane = k*4 + h
        int k = lane >> 2, h = lane & 3;
        int l = max(labels[b * 5 + k], 0);
        int s = slot[l];
        const float4* f4 = (const float4*)(feat + ((size_t)s * 4 + h) * 80);
        const float* pq = polyq + (b * 4 + h) * 16;
        const float* q0 = prfq + ((b * 2 + 0) * 4 + h) * 32;
        const float* q1 = prfq + ((b * 2 + 1) * 4 + h) * 32;

        float pd = 0.f;
#pragma unroll
        for (int j = 0; j < 4; ++j) {
            float4 fp = f4[j];
            pd = fmaf(fp.x, pq[4*j+0], pd);
            pd = fmaf(fp.y, pq[4*j+1], pd);
            pd = fmaf(fp.z, pq[4*j+2], pd);
            pd = fmaf(fp.w, pq[4*j+3], pd);
        }
        float f0 = 0.f, f1 = 0.f;
#pragma unroll
        for (int j = 0; j < 8; ++j) {
            float4 fv = f4[4 + j];
            f0 = fmaf(fv.x, q0[4*j+0], f0);
            f0 = fmaf(fv.y, q0[4*j+1], f0);
            f0 = fmaf(fv.z, q0[4*j+2], f0);
            f0 = fmaf(fv.w, q0[4*j+3], f0);
            float4 fw = f4[12 + j];
            f1 = fmaf(fw.x, q1[4*j+0], f1);
            f1 = fmaf(fw.y, q1[4*j+1], f1);
            f1 = fmaf(fw.z, q1[4*j+2], f1);
            f1 = fmaf(fw.w, q1[4*j+3], f1);
        }
        float c = pd * (f0 + f1);
        c += __shfl_xor(c, 1, 64);                     // sum the 4 heads
        c += __shfl_xor(c, 2, 64);
        if (h == 0) {
            float val = (logf(c + 1e-6f) - logZb) * lmask[b * 5 + k];
            atomicAdd(out, val * (-1.0f / 512.0f));
        }
    }
}

extern "C" void kernel_launch(void* const* d_in, const int* in_sizes, int n_in,
                              void* d_out, int out_size, void* d_ws, size_t ws_size,
                              hipStream_t stream)
{
    const int*   indices = (const int*)  d_in[0];
    const float* mask    = (const float*)d_in[1];
    const int*   labels  = (const int*)  d_in[2];
    const float* lmask   = (const float*)d_in[3];
    const float* emb     = (const float*)d_in[4];
    const float* ck      = (const float*)d_in[5];   // [512][32768]
    const float* omega   = (const float*)d_in[6];   // [2][4][128][32]
    const float* anchors = (const float*)d_in[7];   // [16][128]
    float* ws  = (float*)d_ws;
    float* out = (float*)d_out;
    int*   slot = (int*)(ws + OFF_SLOT);

    k_setup_a<<<64, 256, 0, stream>>>(anchors, omega, slot, ws + OFF_Z, out,
                                      ws + OFF_ANCT, ws + OFF_WPACK);
    k_setup_b<<<10, 256, 0, stream>>>(labels, slot);
    k_embed_feat<<<512, 256, 0, stream>>>(indices, mask, emb, ws + OFF_ANCT, omega,
                                          ws + OFF_POLYQ, ws + OFF_PRFQ);
    k_labels<<<2048, 256, 0, stream>>>(ck, ws + OFF_WPACK, slot,
                                       ws + OFF_FEAT, ws + OFF_ZPART);
    k_zreduce<<<128, 256, 0, stream>>>(ws + OFF_ZPART, ws + OFF_Z);
    k_final<<<128, 256, 0, stream>>>(ws + OFF_POLYQ, ws + OFF_PRFQ, ws + OFF_Z,
                                     labels, lmask, slot, ws + OFF_FEAT, out);
}